// Round 9
// baseline (307.313 us; speedup 1.0000x reference)
//
#include <hip/hip_runtime.h>
#include <math.h>

#define HD 16      // hidden dim
#define NC 4       // num classes
#define BSH 8      // log2(nodes per fine bucket)
#define BSZ 256    // nodes per fine bucket
#define NSB 64     // super-buckets
#define SBSH 12    // log2(nodes per super-bucket)
#define SBN 4096   // nodes per super-bucket
#define CAP1 69632 // per-super-bucket record capacity (mean 62500 + 28 sigma)
#define S2 32      // split-blocks per super-bucket
#define FPB 16     // fine buckets per super-bucket
#define NFB 1024   // fine buckets total
#define CAP2 4352  // per-fine-bucket capacity (mean 3906 + ~7 sigma)
#define NIV 17     // intervals = HD + 1
#define STR 35     // LDS P/Q row stride per node (odd -> conflict-free)
#define SMASK 0x3FFFFu  // low 18 bits = src id

// ---------- tiny prep: sorted relu thresholds + per-feature split/sign ----------
__global__ void k_thr(const float* __restrict__ W1, const float* __restrict__ b1,
                      float* __restrict__ ts, int* __restrict__ splits,
                      int* __restrict__ signs) {
    if (threadIdx.x != 0 || blockIdx.x != 0) return;
    float t[HD], s[HD];
    for (int f = 0; f < HD; ++f) {
        float w = W1[f];
        t[f] = (w != 0.0f) ? (-b1[f] / w) : INFINITY;
        s[f] = t[f];
    }
    for (int i = 1; i < HD; ++i) {            // insertion sort
        float key = s[i]; int j = i - 1;
        while (j >= 0 && s[j] > key) { s[j + 1] = s[j]; --j; }
        s[j + 1] = key;
    }
    for (int f = 0; f < HD; ++f) ts[f] = s[f];
    for (int f = 0; f < HD; ++f) {
        float w = W1[f];
        if (w == 0.0f) { signs[f] = 0; splits[f] = 0; continue; }
        int c = 0;
        for (int g = 0; g < HD; ++g) c += (s[g] < t[f]) ? 1 : 0;
        splits[f] = c + 1;                    // prefix index
        signs[f] = (w > 0.0f) ? 1 : -1;
    }
}

// ---------- pass 1: partition edges into 64 super-buckets ----------
__global__ void k_part1(const int* __restrict__ row, const int* __restrict__ col,
                        int* __restrict__ cursor1, unsigned* __restrict__ bins1,
                        int E, int CHK) {
    __shared__ int hist[NSB];
    __shared__ int lbase[NSB];
    int t = threadIdx.x;
    int cb = blockIdx.x * CHK;
    int ce = min(E, cb + CHK);
    if (t < NSB) hist[t] = 0;
    __syncthreads();
    for (int e = cb + t; e < ce; e += blockDim.x)
        atomicAdd(&hist[col[e] >> SBSH], 1);
    __syncthreads();
    if (t < NSB) {
        int h = hist[t];
        lbase[t] = h ? atomicAdd(&cursor1[t * 16], h) : 0;
        hist[t] = 0;                           // reuse as offsets
    }
    __syncthreads();
    for (int e = cb + t; e < ce; e += blockDim.x) {
        int c = col[e];
        int sb = c >> SBSH;
        int pos = lbase[sb] + atomicAdd(&hist[sb], 1);
        if (pos < CAP1)
            bins1[(size_t)sb * CAP1 + pos] =
                (unsigned)row[e] | ((unsigned)(c & (SBN - 1)) << 18);
    }
}

// ---------- degree per super-bucket (LDS hist, zero divergent ops) ----------
__global__ void k_degA(const unsigned* __restrict__ bins1, const int* __restrict__ cursor1,
                       int* __restrict__ deg, int N) {
    __shared__ int dh[SBN];   // 16 KB
    int t = threadIdx.x;
    int sb = blockIdx.x >> 5;
    int sp = blockIdx.x & (S2 - 1);
    for (int i = t; i < SBN; i += 256) dh[i] = 0;
    __syncthreads();
    int cnt = min(cursor1[sb * 16], CAP1);
    int s0 = sb * CAP1;
    int js = s0 + (int)(((long long)cnt * sp) / S2);
    int je = s0 + (int)(((long long)cnt * (sp + 1)) / S2);
    int j = js + t;
    for (; j + 768 < je; j += 1024) {
        unsigned r0 = bins1[j], r1 = bins1[j + 256], r2 = bins1[j + 512], r3 = bins1[j + 768];
        atomicAdd(&dh[(r0 >> 18) & (SBN - 1)], 1);
        atomicAdd(&dh[(r1 >> 18) & (SBN - 1)], 1);
        atomicAdd(&dh[(r2 >> 18) & (SBN - 1)], 1);
        atomicAdd(&dh[(r3 >> 18) & (SBN - 1)], 1);
    }
    for (; j < je; j += 256) atomicAdd(&dh[(bins1[j] >> 18) & (SBN - 1)], 1);
    __syncthreads();
    int nb = sb << SBSH;
    for (int i = t; i < SBN; i += 256) {
        int h = dh[i];
        int node = nb + i;
        if (h && node < N) atomicAdd(&deg[node], h);
    }
}

// ---------- dx = rsqrt(deg+1) * x ----------
__global__ void k_dinvdx(const int* __restrict__ deg, const float* __restrict__ x,
                         float* __restrict__ dx, int N) {
    int i = blockIdx.x * blockDim.x + threadIdx.x;
    if (i < N) dx[i] = rsqrtf((float)(deg[i] + 1)) * x[i];
}

// ---------- layer-1 partial sums per super-bucket (gather dx, LDS fp32 hist) ----------
__global__ void k_s1B(const unsigned* __restrict__ bins1, const int* __restrict__ cursor1,
                      const float* __restrict__ dx, float* __restrict__ s1p, int N) {
    __shared__ float sacc[SBN];   // 16 KB
    int t = threadIdx.x;
    int sb = blockIdx.x >> 5;
    int sp = blockIdx.x & (S2 - 1);
    for (int i = t; i < SBN; i += 256) sacc[i] = 0.0f;
    __syncthreads();
    int cnt = min(cursor1[sb * 16], CAP1);
    int s0 = sb * CAP1;
    int js = s0 + (int)(((long long)cnt * sp) / S2);
    int je = s0 + (int)(((long long)cnt * (sp + 1)) / S2);
    int j = js + t;
    for (; j + 768 < je; j += 1024) {
        unsigned r0 = bins1[j], r1 = bins1[j + 256], r2 = bins1[j + 512], r3 = bins1[j + 768];
        float v0 = dx[r0 & SMASK], v1 = dx[r1 & SMASK], v2 = dx[r2 & SMASK], v3 = dx[r3 & SMASK];
        atomicAdd(&sacc[(r0 >> 18) & (SBN - 1)], v0);
        atomicAdd(&sacc[(r1 >> 18) & (SBN - 1)], v1);
        atomicAdd(&sacc[(r2 >> 18) & (SBN - 1)], v2);
        atomicAdd(&sacc[(r3 >> 18) & (SBN - 1)], v3);
    }
    for (; j < je; j += 256) {
        unsigned r = bins1[j];
        atomicAdd(&sacc[(r >> 18) & (SBN - 1)], dx[r & SMASK]);
    }
    __syncthreads();
    int nb = sb << SBSH;
    for (int i = t; i < SBN; i += 256) {
        float v = sacc[i];
        int node = nb + i;
        if (v != 0.0f && node < N) unsafeAtomicAdd(&s1p[node], v);
    }
}

// ---------- finalize s1; pack gds2 = {s1 bits, deg} ----------
__global__ void k_fin(const int* __restrict__ deg, const float* __restrict__ s1p,
                      const float* __restrict__ dx, uint2* __restrict__ gds2, int N) {
    int i = blockIdx.x * blockDim.x + threadIdx.x;
    if (i < N) {
        int dg = deg[i];
        float d = rsqrtf((float)(dg + 1));
        float s = d * (s1p[i] + dx[i]);       // + self-loop dinv^2 * x
        gds2[i] = make_uint2(__float_as_uint(s), (unsigned)dg);
    }
}

// ---------- pass 2: fine-bin + gather gds2 + emit 8B payload records ----------
__global__ void k_part2(const unsigned* __restrict__ bins1, const int* __restrict__ cursor1,
                        const uint2* __restrict__ gds2, const float* __restrict__ ts,
                        int* __restrict__ cursor2, uint2* __restrict__ bins2) {
    __shared__ int h4[4][NIV];    // per quarter-wave fine-bucket hist (padded 17)
    __shared__ int o4[4][NIV];    // per quarter-wave running slot cursors
    __shared__ int lb[FPB];
    int t = threadIdx.x;
    int sb = blockIdx.x >> 5;
    int sp = blockIdx.x & (S2 - 1);
    if (t < 4 * NIV) ((int*)h4)[t] = 0;
    __syncthreads();
    int cnt = min(cursor1[sb * 16], CAP1);
    int s0 = sb * CAP1;
    int js = s0 + (int)(((long long)cnt * sp) / S2);
    int je = s0 + (int)(((long long)cnt * (sp + 1)) / S2);
    int cp = (t >> 4) & 3;
    // phase 1: count per fine bucket (per-copy)
    int j = js + t;
    for (; j + 768 < je; j += 1024) {
        atomicAdd(&h4[cp][(bins1[j] >> 26) & 15], 1);
        atomicAdd(&h4[cp][(bins1[j + 256] >> 26) & 15], 1);
        atomicAdd(&h4[cp][(bins1[j + 512] >> 26) & 15], 1);
        atomicAdd(&h4[cp][(bins1[j + 768] >> 26) & 15], 1);
    }
    for (; j < je; j += 256) atomicAdd(&h4[cp][(bins1[j] >> 26) & 15], 1);
    __syncthreads();
    if (t < FPB) {
        int tot = h4[0][t] + h4[1][t] + h4[2][t] + h4[3][t];
        int base = tot ? atomicAdd(&cursor2[(sb * FPB + t) * 16], tot) : 0;
        lb[t] = base;
        o4[0][t] = base;
        o4[1][t] = base + h4[0][t];
        o4[2][t] = base + h4[0][t] + h4[1][t];
        o4[3][t] = base + h4[0][t] + h4[1][t] + h4[2][t];
    }
    float tsr[HD];
    #pragma unroll
    for (int g = 0; g < HD; ++g) tsr[g] = ts[g];
    __syncthreads();
    // phase 2: gather + classify + slotted write
    j = js + t;
    for (; j + 256 < je; j += 512) {
        unsigned rA = bins1[j], rB = bins1[j + 256];
        uint2 gA = gds2[rA & SMASK], gB = gds2[rB & SMASK];
        float sA = __uint_as_float(gA.x), sB = __uint_as_float(gB.x);
        int kA = 0, kB = 0;
        #pragma unroll
        for (int g = 0; g < HD; ++g) { kA += (sA > tsr[g]); kB += (sB > tsr[g]); }
        float dA = rsqrtf((float)(gA.y + 1)), dB = rsqrtf((float)(gB.y + 1));
        int cA = (rA >> 18) & (SBN - 1), cB = (rB >> 18) & (SBN - 1);
        int flA = cA >> BSH, flB = cB >> BSH;
        int pA = atomicAdd(&o4[cp][flA], 1);
        int pB = atomicAdd(&o4[cp][flB], 1);
        if (pA < CAP2)
            bins2[(size_t)(sb * FPB + flA) * CAP2 + pA] =
                make_uint2(__float_as_uint(dA * sA),
                           (unsigned)(cA & (BSZ - 1)) | ((unsigned)kA << 8) | (gA.y << 13));
        if (pB < CAP2)
            bins2[(size_t)(sb * FPB + flB) * CAP2 + pB] =
                make_uint2(__float_as_uint(dB * sB),
                           (unsigned)(cB & (BSZ - 1)) | ((unsigned)kB << 8) | (gB.y << 13));
    }
    for (; j < je; j += 256) {
        unsigned rA = bins1[j];
        uint2 gA = gds2[rA & SMASK];
        float sA = __uint_as_float(gA.x);
        int kA = 0;
        #pragma unroll
        for (int g = 0; g < HD; ++g) kA += (sA > tsr[g]);
        float dA = rsqrtf((float)(gA.y + 1));
        int cA = (rA >> 18) & (SBN - 1);
        int flA = cA >> BSH;
        int pA = atomicAdd(&o4[cp][flA], 1);
        if (pA < CAP2)
            bins2[(size_t)(sb * FPB + flA) * CAP2 + pA] =
                make_uint2(__float_as_uint(dA * sA),
                           (unsigned)(cA & (BSZ - 1)) | ((unsigned)kA << 8) | (gA.y << 13));
    }
}

// ---------- layer-2: gather-free interval aggregation + fused epilogue ----------
__global__ void __launch_bounds__(256, 1)
k_agg(const uint2* __restrict__ bins2, const int* __restrict__ cursor2,
      const uint2* __restrict__ gds2,
      const int* __restrict__ splits, const int* __restrict__ signs,
      const float* __restrict__ W1, const float* __restrict__ b1,
      const float* __restrict__ W2, const float* __restrict__ b2,
      const float* __restrict__ Wfc, const float* __restrict__ bfc,
      float* __restrict__ out, int N) {
    __shared__ float acc[BSZ * STR];   // 35.8 KB
    int t = threadIdx.x, b = blockIdx.x;
    for (int i = t; i < BSZ * STR; i += 256) acc[i] = 0.0f;
    __syncthreads();
    int s = 0, e = min(cursor2[b * 16], CAP2);
    const uint2* bb = bins2 + (size_t)b * CAP2;
    int j = s + t;
    for (; j + 768 < e; j += 1024) {
        uint2 r0 = bb[j], r1 = bb[j + 256], r2 = bb[j + 512], r3 = bb[j + 768];
        float* a0 = &acc[(int)(r0.y & 255) * STR + 2 * ((r0.y >> 8) & 31)];
        float* a1 = &acc[(int)(r1.y & 255) * STR + 2 * ((r1.y >> 8) & 31)];
        float* a2 = &acc[(int)(r2.y & 255) * STR + 2 * ((r2.y >> 8) & 31)];
        float* a3 = &acc[(int)(r3.y & 255) * STR + 2 * ((r3.y >> 8) & 31)];
        atomicAdd(a0, __uint_as_float(r0.x)); atomicAdd(a0 + 1, rsqrtf((float)((r0.y >> 13) + 1)));
        atomicAdd(a1, __uint_as_float(r1.x)); atomicAdd(a1 + 1, rsqrtf((float)((r1.y >> 13) + 1)));
        atomicAdd(a2, __uint_as_float(r2.x)); atomicAdd(a2 + 1, rsqrtf((float)((r2.y >> 13) + 1)));
        atomicAdd(a3, __uint_as_float(r3.x)); atomicAdd(a3 + 1, rsqrtf((float)((r3.y >> 13) + 1)));
    }
    for (; j < e; j += 256) {
        uint2 r = bb[j];
        float* a = &acc[(int)(r.y & 255) * STR + 2 * ((r.y >> 8) & 31)];
        atomicAdd(a, __uint_as_float(r.x));
        atomicAdd(a + 1, rsqrtf((float)((r.y >> 13) + 1)));
    }
    __syncthreads();

    // ---- reconstruction + epilogue ----
    int node = (b << BSH) + t;
    if (node >= N) return;
    float Ppre[NIV + 1], Qpre[NIV + 1];
    float pp = 0.0f, qq = 0.0f;
    #pragma unroll
    for (int m = 0; m < NIV; ++m) {
        Ppre[m] = pp; Qpre[m] = qq;
        pp += acc[t * STR + 2 * m];
        qq += acc[t * STR + 2 * m + 1];
    }
    Ppre[NIV] = pp; Qpre[NIV] = qq;

    uint2 gi = gds2[node];
    float si = __uint_as_float(gi.x);
    float di = rsqrtf((float)(gi.y + 1));
    float aggv[HD];
    #pragma unroll
    for (int f = 0; f < HD; ++f) {
        int sp = splits[f], sg = signs[f];
        float w = W1[f], bbv = b1[f];
        float A, B;
        if (sg > 0)      { A = pp - Ppre[sp]; B = qq - Qpre[sp]; }
        else if (sg < 0) { A = Ppre[sp];      B = Qpre[sp]; }
        else             { A = 0.0f;          B = (bbv > 0.0f) ? qq : 0.0f; }
        float selfh = fmaxf(fmaf(w, si, bbv), 0.0f);
        aggv[f] = di * (fmaf(w, A, bbv * B) + di * selfh);
    }
    float o0 = bfc[0], o1 = bfc[1], o2 = bfc[2], o3 = bfc[3];
    #pragma unroll
    for (int f2 = 0; f2 < HD; ++f2) {
        float h = b2[f2];
        #pragma unroll
        for (int k = 0; k < HD; ++k) h = fmaf(aggv[k], W2[k * HD + f2], h);
        h = fmaxf(h, 0.0f);
        o0 = fmaf(h, Wfc[f2 * NC + 0], o0);
        o1 = fmaf(h, Wfc[f2 * NC + 1], o1);
        o2 = fmaf(h, Wfc[f2 * NC + 2], o2);
        o3 = fmaf(h, Wfc[f2 * NC + 3], o3);
    }
    ((float4*)out)[node] = make_float4(o0, o1, o2, o3);
}

extern "C" void kernel_launch(void* const* d_in, const int* in_sizes, int n_in,
                              void* d_out, int out_size, void* d_ws, size_t ws_size,
                              hipStream_t stream) {
    const float* x   = (const float*)d_in[0];
    const int*   ei  = (const int*)d_in[1];
    const float* W1  = (const float*)d_in[2];
    const float* b1  = (const float*)d_in[3];
    const float* W2  = (const float*)d_in[4];
    const float* b2  = (const float*)d_in[5];
    const float* Wfc = (const float*)d_in[6];
    const float* bfc = (const float*)d_in[7];
    float* out = (float*)d_out;

    const int N = in_sizes[0];            // 250000 (< 2^18)
    const int E = in_sizes[1] / 2;        // 4000000
    const int* row = ei;
    const int* col = ei + E;

    // workspace layout (~58 MB)
    char* ws = (char*)d_ws;
    size_t off = 0;
    unsigned* bins1 = (unsigned*)(ws + off); off += (size_t)NSB * CAP1 * 4;   // 17.8 MB
    uint2*  bins2 = (uint2*)(ws + off);    off += (size_t)NFB * CAP2 * 8;     // 35.7 MB
    size_t zoff = off;   // zero region: cursor1, cursor2, deg, s1p
    int*    cursor1= (int*)(ws + off);   off += (size_t)NSB * 16 * 4;
    int*    cursor2= (int*)(ws + off);   off += (size_t)NFB * 16 * 4;
    int*    deg   = (int*)(ws + off);    off += (size_t)N * 4;
    float*  s1p   = (float*)(ws + off);  off += (size_t)N * 4;
    size_t zlen = off - zoff;
    float*  dx    = (float*)(ws + off);  off += (size_t)N * 4;
    uint2*  gds2  = (uint2*)(ws + off);  off += (size_t)N * 8;
    float*  ts    = (float*)(ws + off);  off += 64;
    int*    splits= (int*)(ws + off);    off += 64;
    int*    signs = (int*)(ws + off);    off += 64;

    hipMemsetAsync(ws + zoff, 0, zlen, stream);

    const int B = 256;
    k_thr<<<1, 64, 0, stream>>>(W1, b1, ts, splits, signs);
    const int G1 = 1024;
    const int CHK = (E + G1 - 1) / G1;
    k_part1<<<G1, B, 0, stream>>>(row, col, cursor1, bins1, E, CHK);
    k_degA<<<NSB * S2, B, 0, stream>>>(bins1, cursor1, deg, N);
    k_dinvdx<<<(N + B - 1) / B, B, 0, stream>>>(deg, x, dx, N);
    k_s1B<<<NSB * S2, B, 0, stream>>>(bins1, cursor1, dx, s1p, N);
    k_fin<<<(N + B - 1) / B, B, 0, stream>>>(deg, s1p, dx, gds2, N);
    k_part2<<<NSB * S2, B, 0, stream>>>(bins1, cursor1, gds2, ts, cursor2, bins2);
    k_agg<<<NFB, B, 0, stream>>>(bins2, cursor2, gds2, splits, signs,
                                 W1, b1, W2, b2, Wfc, bfc, out, N);
}

// Round 10
// 287.956 us; speedup vs baseline: 1.0672x; 1.0672x over previous
//
#include <hip/hip_runtime.h>
#include <math.h>

#define HD 16      // hidden dim
#define NC 4       // num classes
#define NSB 64     // super-buckets
#define SBSH 12    // log2 nodes per super-bucket
#define SBN 4096   // nodes per super-bucket
#define CAP1 69632 // per-super-bucket record capacity (mean 62500 + 28 sigma)
#define NCH 8      // dst-chunks per super-bucket in k_agg2
#define CHSH 9     // log2 nodes per chunk
#define CHN 512    // nodes per chunk
#define S2 8       // split-blocks per super-bucket for degA/s1B
#define NIV 17     // intervals = HD + 1
#define STR 35     // LDS P/Q row stride per node (odd -> conflict-free)
#define SMASK 0x3FFFFu  // low 18 bits = src id

// ---------- tiny prep: sorted relu thresholds + per-feature split/sign ----------
__global__ void k_thr(const float* __restrict__ W1, const float* __restrict__ b1,
                      float* __restrict__ ts, int* __restrict__ splits,
                      int* __restrict__ signs) {
    if (threadIdx.x != 0 || blockIdx.x != 0) return;
    float t[HD], s[HD];
    for (int f = 0; f < HD; ++f) {
        float w = W1[f];
        t[f] = (w != 0.0f) ? (-b1[f] / w) : INFINITY;
        s[f] = t[f];
    }
    for (int i = 1; i < HD; ++i) {            // insertion sort
        float key = s[i]; int j = i - 1;
        while (j >= 0 && s[j] > key) { s[j + 1] = s[j]; --j; }
        s[j + 1] = key;
    }
    for (int f = 0; f < HD; ++f) ts[f] = s[f];
    for (int f = 0; f < HD; ++f) {
        float w = W1[f];
        if (w == 0.0f) { signs[f] = 0; splits[f] = 0; continue; }
        int c = 0;
        for (int g = 0; g < HD; ++g) c += (s[g] < t[f]) ? 1 : 0;
        splits[f] = c + 1;                    // prefix index
        signs[f] = (w > 0.0f) ? 1 : -1;
    }
}

// ---------- pass 1: partition edges into 64 super-buckets ----------
__global__ void k_part1(const int* __restrict__ row, const int* __restrict__ col,
                        int* __restrict__ cursor1, unsigned* __restrict__ bins1,
                        int E, int CHK) {
    __shared__ int hist[NSB];
    __shared__ int lbase[NSB];
    int t = threadIdx.x;
    int cb = blockIdx.x * CHK;
    int ce = min(E, cb + CHK);
    if (t < NSB) hist[t] = 0;
    __syncthreads();
    for (int e = cb + t; e < ce; e += blockDim.x)
        atomicAdd(&hist[col[e] >> SBSH], 1);
    __syncthreads();
    if (t < NSB) {
        int h = hist[t];
        lbase[t] = h ? atomicAdd(&cursor1[t * 16], h) : 0;
        hist[t] = 0;                           // reuse as offsets
    }
    __syncthreads();
    for (int e = cb + t; e < ce; e += blockDim.x) {
        int c = col[e];
        int sb = c >> SBSH;
        int pos = lbase[sb] + atomicAdd(&hist[sb], 1);
        if (pos < CAP1)
            bins1[(size_t)sb * CAP1 + pos] =
                (unsigned)row[e] | ((unsigned)(c & (SBN - 1)) << 18);
    }
}

// ---------- degree per super-bucket (uint4 stream, LDS hist) ----------
__global__ void k_degA(const unsigned* __restrict__ bins1, const int* __restrict__ cursor1,
                       int* __restrict__ deg, int N) {
    __shared__ int dh[SBN];   // 16 KB
    int t = threadIdx.x;
    int sb = blockIdx.x >> 3;
    int sp = blockIdx.x & (S2 - 1);
    for (int i = t; i < SBN; i += 256) dh[i] = 0;
    __syncthreads();
    int cnt = min(cursor1[sb * 16], CAP1);
    const unsigned* bp = bins1 + (size_t)sb * CAP1;
    int nfull = cnt & ~2047;
    for (int it = sp * 2048; it < nfull; it += S2 * 2048) {
        uint4 ra = *(const uint4*)(bp + it + 4 * t);
        uint4 rb = *(const uint4*)(bp + it + 1024 + 4 * t);
        atomicAdd(&dh[ra.x >> 18], 1); atomicAdd(&dh[ra.y >> 18], 1);
        atomicAdd(&dh[ra.z >> 18], 1); atomicAdd(&dh[ra.w >> 18], 1);
        atomicAdd(&dh[rb.x >> 18], 1); atomicAdd(&dh[rb.y >> 18], 1);
        atomicAdd(&dh[rb.z >> 18], 1); atomicAdd(&dh[rb.w >> 18], 1);
    }
    if (sp == S2 - 1)
        for (int j = nfull + t; j < cnt; j += 256) atomicAdd(&dh[bp[j] >> 18], 1);
    __syncthreads();
    int nb = sb << SBSH;
    for (int i = t; i < SBN; i += 256) {
        int h = dh[i];
        int node = nb + i;
        if (h && node < N) atomicAdd(&deg[node], h);
    }
}

// ---------- dx = rsqrt(deg+1) * x ----------
__global__ void k_dinvdx(const int* __restrict__ deg, const float* __restrict__ x,
                         float* __restrict__ dx, int N) {
    int i = blockIdx.x * blockDim.x + threadIdx.x;
    if (i < N) dx[i] = rsqrtf((float)(deg[i] + 1)) * x[i];
}

// ---------- layer-1 partial sums per super-bucket (uint4 stream + dx gather) ----------
__global__ void k_s1B(const unsigned* __restrict__ bins1, const int* __restrict__ cursor1,
                      const float* __restrict__ dx, float* __restrict__ s1p, int N) {
    __shared__ float sacc[SBN];   // 16 KB
    int t = threadIdx.x;
    int sb = blockIdx.x >> 3;
    int sp = blockIdx.x & (S2 - 1);
    for (int i = t; i < SBN; i += 256) sacc[i] = 0.0f;
    __syncthreads();
    int cnt = min(cursor1[sb * 16], CAP1);
    const unsigned* bp = bins1 + (size_t)sb * CAP1;
    int nfull = cnt & ~2047;
    for (int it = sp * 2048; it < nfull; it += S2 * 2048) {
        uint4 ra = *(const uint4*)(bp + it + 4 * t);
        uint4 rb = *(const uint4*)(bp + it + 1024 + 4 * t);
        float v0 = dx[ra.x & SMASK], v1 = dx[ra.y & SMASK];
        float v2 = dx[ra.z & SMASK], v3 = dx[ra.w & SMASK];
        float v4 = dx[rb.x & SMASK], v5 = dx[rb.y & SMASK];
        float v6 = dx[rb.z & SMASK], v7 = dx[rb.w & SMASK];
        atomicAdd(&sacc[ra.x >> 18], v0); atomicAdd(&sacc[ra.y >> 18], v1);
        atomicAdd(&sacc[ra.z >> 18], v2); atomicAdd(&sacc[ra.w >> 18], v3);
        atomicAdd(&sacc[rb.x >> 18], v4); atomicAdd(&sacc[rb.y >> 18], v5);
        atomicAdd(&sacc[rb.z >> 18], v6); atomicAdd(&sacc[rb.w >> 18], v7);
    }
    if (sp == S2 - 1)
        for (int j = nfull + t; j < cnt; j += 256) {
            unsigned r = bp[j];
            atomicAdd(&sacc[r >> 18], dx[r & SMASK]);
        }
    __syncthreads();
    int nb = sb << SBSH;
    for (int i = t; i < SBN; i += 256) {
        float v = sacc[i];
        int node = nb + i;
        if (v != 0.0f && node < N) unsafeAtomicAdd(&s1p[node], v);
    }
}

// ---------- finalize s1; pack gds2 = {s1 bits, deg} ----------
__global__ void k_fin(const int* __restrict__ deg, const float* __restrict__ s1p,
                      const float* __restrict__ dx, uint2* __restrict__ gds2, int N) {
    int i = blockIdx.x * blockDim.x + threadIdx.x;
    if (i < N) {
        int dg = deg[i];
        float d = rsqrtf((float)(dg + 1));
        float s = d * (s1p[i] + dx[i]);       // + self-loop dinv^2 * x
        gds2[i] = make_uint2(__float_as_uint(s), (unsigned)dg);
    }
}

// ---------- layer-2: replicated-read chunked aggregation + fused epilogue ----------
// block = ch*64 + sb : all 8 chunks of a super-bucket land on the same XCD (%8)
__global__ void __launch_bounds__(256, 2)
k_agg2(const unsigned* __restrict__ bins1, const int* __restrict__ cursor1,
       const uint2* __restrict__ gds2, const float* __restrict__ ts,
       const int* __restrict__ splits, const int* __restrict__ signs,
       const float* __restrict__ W1, const float* __restrict__ b1,
       const float* __restrict__ W2, const float* __restrict__ b2,
       const float* __restrict__ Wfc, const float* __restrict__ bfc,
       float* __restrict__ out, int N) {
    __shared__ float acc[CHN * STR];   // 71.7 KB -> 2 blocks/CU
    int t = threadIdx.x;
    int sb = blockIdx.x & (NSB - 1);
    unsigned ch = (unsigned)(blockIdx.x >> 6);   // 0..7
    for (int i = t; i < CHN * STR; i += 256) acc[i] = 0.0f;
    float tsr[HD];
    #pragma unroll
    for (int g = 0; g < HD; ++g) tsr[g] = ts[g];
    __syncthreads();

    int cnt = min(cursor1[sb * 16], CAP1);
    const unsigned* bp = bins1 + (size_t)sb * CAP1;

#define PROC(r) do { \
        unsigned dl = (r) >> 18; \
        if ((dl >> CHSH) == ch) { \
            uint2 g = gds2[(r) & SMASK]; \
            float sv = __uint_as_float(g.x); \
            int k = 0; \
            _Pragma("unroll") \
            for (int gg = 0; gg < HD; ++gg) k += (sv > tsr[gg]); \
            float dv = rsqrtf((float)(g.y + 1)); \
            float* a = &acc[(int)(dl & (CHN - 1)) * STR + 2 * k]; \
            atomicAdd(a, dv * sv); \
            atomicAdd(a + 1, dv); \
        } \
    } while (0)

    int nfull = cnt & ~2047;
    for (int it = 0; it < nfull; it += 2048) {
        uint4 ra = *(const uint4*)(bp + it + 4 * t);
        uint4 rb = *(const uint4*)(bp + it + 1024 + 4 * t);
        PROC(ra.x); PROC(ra.y); PROC(ra.z); PROC(ra.w);
        PROC(rb.x); PROC(rb.y); PROC(rb.z); PROC(rb.w);
    }
    for (int j = nfull + t; j < cnt; j += 256) { unsigned r = bp[j]; PROC(r); }
#undef PROC
    __syncthreads();

    // ---- reconstruction + epilogue: 512 nodes, 2 per thread ----
    int base = (sb << SBSH) + ((int)ch << CHSH);
    for (int l = t; l < CHN; l += 256) {
        int node = base + l;
        if (node >= N) continue;
        float Ppre[NIV + 1], Qpre[NIV + 1];
        float pp = 0.0f, qq = 0.0f;
        #pragma unroll
        for (int m = 0; m < NIV; ++m) {
            Ppre[m] = pp; Qpre[m] = qq;
            pp += acc[l * STR + 2 * m];
            qq += acc[l * STR + 2 * m + 1];
        }
        Ppre[NIV] = pp; Qpre[NIV] = qq;

        uint2 gi = gds2[node];
        float si = __uint_as_float(gi.x);
        float di = rsqrtf((float)(gi.y + 1));
        float aggv[HD];
        #pragma unroll
        for (int f = 0; f < HD; ++f) {
            int sp = splits[f], sg = signs[f];
            float w = W1[f], bbv = b1[f];
            float A, B;
            if (sg > 0)      { A = pp - Ppre[sp]; B = qq - Qpre[sp]; }
            else if (sg < 0) { A = Ppre[sp];      B = Qpre[sp]; }
            else             { A = 0.0f;          B = (bbv > 0.0f) ? qq : 0.0f; }
            float selfh = fmaxf(fmaf(w, si, bbv), 0.0f);
            aggv[f] = di * (fmaf(w, A, bbv * B) + di * selfh);
        }
        float o0 = bfc[0], o1 = bfc[1], o2 = bfc[2], o3 = bfc[3];
        #pragma unroll
        for (int f2 = 0; f2 < HD; ++f2) {
            float h = b2[f2];
            #pragma unroll
            for (int k = 0; k < HD; ++k) h = fmaf(aggv[k], W2[k * HD + f2], h);
            h = fmaxf(h, 0.0f);
            o0 = fmaf(h, Wfc[f2 * NC + 0], o0);
            o1 = fmaf(h, Wfc[f2 * NC + 1], o1);
            o2 = fmaf(h, Wfc[f2 * NC + 2], o2);
            o3 = fmaf(h, Wfc[f2 * NC + 3], o3);
        }
        ((float4*)out)[node] = make_float4(o0, o1, o2, o3);
    }
}

extern "C" void kernel_launch(void* const* d_in, const int* in_sizes, int n_in,
                              void* d_out, int out_size, void* d_ws, size_t ws_size,
                              hipStream_t stream) {
    const float* x   = (const float*)d_in[0];
    const int*   ei  = (const int*)d_in[1];
    const float* W1  = (const float*)d_in[2];
    const float* b1  = (const float*)d_in[3];
    const float* W2  = (const float*)d_in[4];
    const float* b2  = (const float*)d_in[5];
    const float* Wfc = (const float*)d_in[6];
    const float* bfc = (const float*)d_in[7];
    float* out = (float*)d_out;

    const int N = in_sizes[0];            // 250000 (< 2^18)
    const int E = in_sizes[1] / 2;        // 4000000
    const int* row = ei;
    const int* col = ei + E;

    // workspace layout (~23 MB)
    char* ws = (char*)d_ws;
    size_t off = 0;
    unsigned* bins1 = (unsigned*)(ws + off); off += (size_t)NSB * CAP1 * 4;   // 17.8 MB
    size_t zoff = off;   // zero region: cursor1, deg, s1p
    int*    cursor1= (int*)(ws + off);   off += (size_t)NSB * 16 * 4;         // 4 KB
    int*    deg   = (int*)(ws + off);    off += (size_t)N * 4;                // 1 MB
    float*  s1p   = (float*)(ws + off);  off += (size_t)N * 4;                // 1 MB
    size_t zlen = off - zoff;
    float*  dx    = (float*)(ws + off);  off += (size_t)N * 4;
    uint2*  gds2  = (uint2*)(ws + off);  off += (size_t)N * 8;
    float*  ts    = (float*)(ws + off);  off += 64;
    int*    splits= (int*)(ws + off);    off += 64;
    int*    signs = (int*)(ws + off);    off += 64;

    hipMemsetAsync(ws + zoff, 0, zlen, stream);

    const int B = 256;
    k_thr<<<1, 64, 0, stream>>>(W1, b1, ts, splits, signs);
    const int G1 = 1024;
    const int CHK = (E + G1 - 1) / G1;
    k_part1<<<G1, B, 0, stream>>>(row, col, cursor1, bins1, E, CHK);
    k_degA<<<NSB * S2, B, 0, stream>>>(bins1, cursor1, deg, N);
    k_dinvdx<<<(N + B - 1) / B, B, 0, stream>>>(deg, x, dx, N);
    k_s1B<<<NSB * S2, B, 0, stream>>>(bins1, cursor1, dx, s1p, N);
    k_fin<<<(N + B - 1) / B, B, 0, stream>>>(deg, s1p, dx, gds2, N);
    k_agg2<<<NSB * NCH, B, 0, stream>>>(bins1, cursor1, gds2, ts, splits, signs,
                                        W1, b1, W2, b2, Wfc, bfc, out, N);
}

// Round 11
// 243.524 us; speedup vs baseline: 1.2619x; 1.1825x over previous
//
#include <hip/hip_runtime.h>
#include <math.h>

#define HD 16      // hidden dim
#define NC 4       // num classes
#define BSH 8      // log2(nodes per fine bucket)
#define BSZ 256    // nodes per fine bucket
#define NSB 64     // super-buckets
#define SBSH 12    // log2 nodes per super-bucket
#define SBN 4096   // nodes per super-bucket
#define CAP1 69632 // per-super-bucket capacity (mean 62500 + 28 sigma), mult of 1024
#define S2 16      // split-blocks per super-bucket in pass 2
#define FPB 16     // fine buckets per super-bucket
#define NFB 1024   // fine buckets total
#define CAP2 5120  // per-fine-bucket capacity (mean 3906 + ~19 sigma), mult of 4
#define NIV 17     // intervals = HD + 1
#define STR 35     // LDS P/Q row stride per node (odd -> conflict-free)
#define SMASK 0x3FFFFu  // low 18 bits = src id

// ---------- tiny prep: sorted relu thresholds + per-feature split/sign ----------
__global__ void k_thr(const float* __restrict__ W1, const float* __restrict__ b1,
                      float* __restrict__ ts, int* __restrict__ splits,
                      int* __restrict__ signs) {
    if (threadIdx.x != 0 || blockIdx.x != 0) return;
    float t[HD], s[HD];
    for (int f = 0; f < HD; ++f) {
        float w = W1[f];
        t[f] = (w != 0.0f) ? (-b1[f] / w) : INFINITY;
        s[f] = t[f];
    }
    for (int i = 1; i < HD; ++i) {            // insertion sort
        float key = s[i]; int j = i - 1;
        while (j >= 0 && s[j] > key) { s[j + 1] = s[j]; --j; }
        s[j + 1] = key;
    }
    for (int f = 0; f < HD; ++f) ts[f] = s[f];
    for (int f = 0; f < HD; ++f) {
        float w = W1[f];
        if (w == 0.0f) { signs[f] = 0; splits[f] = 0; continue; }
        int c = 0;
        for (int g = 0; g < HD; ++g) c += (s[g] < t[f]) ? 1 : 0;
        splits[f] = c + 1;                    // prefix index
        signs[f] = (w > 0.0f) ? 1 : -1;
    }
}

// ---------- pass 1: partition into 64 super-buckets (4-copy hist, uint4) ----------
#define CHK 4096
__global__ void k_part1(const unsigned* __restrict__ row, const unsigned* __restrict__ col,
                        int* __restrict__ cursor1, unsigned* __restrict__ bins1, int E) {
    __shared__ int h4[4][NSB];    // quarter-wave copies
    __shared__ int b4[4][NSB];    // per-copy write cursors
    int t = threadIdx.x;
    int cp = (t >> 4) & 3;
    int cb = blockIdx.x * CHK;
    int ce = min(E, cb + CHK);
    if (ce <= cb) return;
    for (int i = t; i < 4 * NSB; i += 256) ((int*)h4)[i] = 0;
    __syncthreads();
    int len = ce - cb;
    int nfull = len & ~1023;
    for (int it = 0; it < nfull; it += 1024) {
        uint4 c4 = *(const uint4*)(col + cb + it + 4 * t);
        atomicAdd(&h4[cp][c4.x >> SBSH], 1);
        atomicAdd(&h4[cp][c4.y >> SBSH], 1);
        atomicAdd(&h4[cp][c4.z >> SBSH], 1);
        atomicAdd(&h4[cp][c4.w >> SBSH], 1);
    }
    for (int j = cb + nfull + t; j < ce; j += 256)
        atomicAdd(&h4[cp][col[j] >> SBSH], 1);
    __syncthreads();
    if (t < NSB) {
        int h0 = h4[0][t], h1 = h4[1][t], h2 = h4[2][t], h3 = h4[3][t];
        int tot = h0 + h1 + h2 + h3;
        int base = tot ? atomicAdd(&cursor1[t * 16], tot) : 0;
        b4[0][t] = base;
        b4[1][t] = base + h0;
        b4[2][t] = base + h0 + h1;
        b4[3][t] = base + h0 + h1 + h2;
    }
    __syncthreads();
#define EMIT1(cv, rv) do { \
        int sb_ = (int)((cv) >> SBSH); \
        int pos_ = atomicAdd(&b4[cp][sb_], 1); \
        if (pos_ < CAP1) \
            bins1[(size_t)sb_ * CAP1 + pos_] = (rv) | (((cv) & (SBN - 1)) << 18); \
    } while (0)
    for (int it = 0; it < nfull; it += 1024) {
        uint4 c4 = *(const uint4*)(col + cb + it + 4 * t);
        uint4 r4 = *(const uint4*)(row + cb + it + 4 * t);
        EMIT1(c4.x, r4.x); EMIT1(c4.y, r4.y);
        EMIT1(c4.z, r4.z); EMIT1(c4.w, r4.w);
    }
    for (int j = cb + nfull + t; j < ce; j += 256) EMIT1(col[j], row[j]);
#undef EMIT1
}

// ---------- pass 2: split each super-bucket into 16 fine buckets (4-copy slots) ----------
__global__ void k_part2(const unsigned* __restrict__ bins1, const int* __restrict__ cursor1,
                        int* __restrict__ cursor2, unsigned* __restrict__ bins2) {
    __shared__ int h4[4][NIV];    // quarter-wave fine hist (padded 17)
    __shared__ int o4[4][NIV];    // quarter-wave slot cursors
    int t = threadIdx.x;
    int sb = blockIdx.x >> 4;
    int sp = blockIdx.x & (S2 - 1);
    int cp = (t >> 4) & 3;
    if (t < 4 * NIV) ((int*)h4)[t] = 0;
    __syncthreads();
    int cnt = min(cursor1[sb * 16], CAP1);
    const unsigned* bp = bins1 + (size_t)sb * CAP1;
    int nfull = cnt & ~1023;
    // phase 1: count (chunk-strided coverage; same traversal in both phases)
    for (int it = sp * 1024; it < nfull; it += S2 * 1024) {
        uint4 r = *(const uint4*)(bp + it + 4 * t);
        atomicAdd(&h4[cp][r.x >> 26], 1);
        atomicAdd(&h4[cp][r.y >> 26], 1);
        atomicAdd(&h4[cp][r.z >> 26], 1);
        atomicAdd(&h4[cp][r.w >> 26], 1);
    }
    if (sp == S2 - 1)
        for (int j = nfull + t; j < cnt; j += 256)
            atomicAdd(&h4[cp][bp[j] >> 26], 1);
    __syncthreads();
    if (t < FPB) {
        int h0 = h4[0][t], h1 = h4[1][t], h2 = h4[2][t], h3 = h4[3][t];
        int tot = h0 + h1 + h2 + h3;
        int base = tot ? atomicAdd(&cursor2[(sb * FPB + t) * 16], tot) : 0;
        o4[0][t] = base;
        o4[1][t] = base + h0;
        o4[2][t] = base + h0 + h1;
        o4[3][t] = base + h0 + h1 + h2;
    }
    __syncthreads();
#define EMIT2(r) do { \
        int fl_ = (int)((r) >> 26); \
        int pos_ = atomicAdd(&o4[cp][fl_], 1); \
        if (pos_ < CAP2) \
            bins2[(size_t)(sb * FPB + fl_) * CAP2 + pos_] = \
                ((r) & SMASK) | ((((r) >> 18) & (BSZ - 1)) << 18); \
    } while (0)
    for (int it = sp * 1024; it < nfull; it += S2 * 1024) {
        uint4 r = *(const uint4*)(bp + it + 4 * t);
        EMIT2(r.x); EMIT2(r.y); EMIT2(r.z); EMIT2(r.w);
    }
    if (sp == S2 - 1)
        for (int j = nfull + t; j < cnt; j += 256) { unsigned r = bp[j]; EMIT2(r); }
#undef EMIT2
}

// ---------- fused degree + dinv + dx (per fine bucket, uint4) ----------
__global__ void k_degdx(const unsigned* __restrict__ bins, const int* __restrict__ cursor,
                        const float* __restrict__ x,
                        float* __restrict__ dinv, float* __restrict__ dx, int N) {
    __shared__ int cnt[BSZ];
    int t = threadIdx.x, b = blockIdx.x;
    cnt[t] = 0;
    __syncthreads();
    int e = min(cursor[b * 16], CAP2);
    const unsigned* bp = bins + (size_t)b * CAP2;
    int nfull = e & ~1023;
    for (int it = 0; it < nfull; it += 1024) {
        uint4 r = *(const uint4*)(bp + it + 4 * t);
        atomicAdd(&cnt[r.x >> 18], 1);
        atomicAdd(&cnt[r.y >> 18], 1);
        atomicAdd(&cnt[r.z >> 18], 1);
        atomicAdd(&cnt[r.w >> 18], 1);
    }
    for (int j = nfull + t; j < e; j += 256) atomicAdd(&cnt[bp[j] >> 18], 1);
    __syncthreads();
    int node = (b << BSH) + t;
    if (node < N) {
        float d = rsqrtf((float)(cnt[t] + 1));
        dinv[node] = d;
        dx[node] = d * x[node];
    }
}

// ---------- layer-1 scalar aggregate (per fine bucket, uint4) ----------
__global__ void k_s1(const unsigned* __restrict__ bins, const int* __restrict__ cursor,
                     const float* __restrict__ dinv, const float* __restrict__ dx,
                     float2* __restrict__ gds, int N) {
    __shared__ float sacc[BSZ];
    int t = threadIdx.x, b = blockIdx.x;
    sacc[t] = 0.0f;
    __syncthreads();
    int e = min(cursor[b * 16], CAP2);
    const unsigned* bp = bins + (size_t)b * CAP2;
    int nfull = e & ~1023;
    for (int it = 0; it < nfull; it += 1024) {
        uint4 r = *(const uint4*)(bp + it + 4 * t);
        float v0 = dx[r.x & SMASK], v1 = dx[r.y & SMASK];
        float v2 = dx[r.z & SMASK], v3 = dx[r.w & SMASK];
        atomicAdd(&sacc[r.x >> 18], v0);
        atomicAdd(&sacc[r.y >> 18], v1);
        atomicAdd(&sacc[r.z >> 18], v2);
        atomicAdd(&sacc[r.w >> 18], v3);
    }
    for (int j = nfull + t; j < e; j += 256) {
        unsigned r = bp[j];
        atomicAdd(&sacc[r >> 18], dx[r & SMASK]);
    }
    __syncthreads();
    int node = (b << BSH) + t;
    if (node < N) {
        float d = dinv[node];
        gds[node] = make_float2(d, d * (sacc[t] + dx[node]));  // + self-loop dinv^2*x
    }
}

// ---------- layer-2: interval-bucketed LDS aggregate + fused recon/epilogue ----------
__global__ void __launch_bounds__(256, 1)
k_agg(const unsigned* __restrict__ bins, const int* __restrict__ cursor,
      const float2* __restrict__ gds, const float* __restrict__ ts,
      const int* __restrict__ splits, const int* __restrict__ signs,
      const float* __restrict__ W1, const float* __restrict__ b1,
      const float* __restrict__ W2, const float* __restrict__ b2,
      const float* __restrict__ Wfc, const float* __restrict__ bfc,
      float* __restrict__ out, int N) {
    __shared__ float acc[BSZ * STR];   // 35.8 KB -> 4 blocks/CU
    int t = threadIdx.x, b = blockIdx.x;
    for (int i = t; i < BSZ * STR; i += 256) acc[i] = 0.0f;
    float tsr[HD];
    #pragma unroll
    for (int g = 0; g < HD; ++g) tsr[g] = ts[g];
    __syncthreads();

    int e = min(cursor[b * 16], CAP2);
    const unsigned* bp = bins + (size_t)b * CAP2;
    int nfull = e & ~1023;
    for (int it = 0; it < nfull; it += 1024) {
        uint4 r = *(const uint4*)(bp + it + 4 * t);
        float2 p0 = gds[r.x & SMASK], p1 = gds[r.y & SMASK],
               p2 = gds[r.z & SMASK], p3 = gds[r.w & SMASK];
        int k0 = 0, k1 = 0, k2 = 0, k3 = 0;
        #pragma unroll
        for (int g = 0; g < HD; ++g) {
            k0 += (p0.y > tsr[g]); k1 += (p1.y > tsr[g]);
            k2 += (p2.y > tsr[g]); k3 += (p3.y > tsr[g]);
        }
        float* a0 = &acc[(int)(r.x >> 18) * STR + 2 * k0];
        float* a1 = &acc[(int)(r.y >> 18) * STR + 2 * k1];
        float* a2 = &acc[(int)(r.z >> 18) * STR + 2 * k2];
        float* a3 = &acc[(int)(r.w >> 18) * STR + 2 * k3];
        atomicAdd(a0, p0.x * p0.y); atomicAdd(a0 + 1, p0.x);
        atomicAdd(a1, p1.x * p1.y); atomicAdd(a1 + 1, p1.x);
        atomicAdd(a2, p2.x * p2.y); atomicAdd(a2 + 1, p2.x);
        atomicAdd(a3, p3.x * p3.y); atomicAdd(a3 + 1, p3.x);
    }
    for (int j = nfull + t; j < e; j += 256) {
        unsigned r = bp[j];
        float2 p = gds[r & SMASK];
        int k = 0;
        #pragma unroll
        for (int g = 0; g < HD; ++g) k += (p.y > tsr[g]);
        float* a = &acc[(int)(r >> 18) * STR + 2 * k];
        atomicAdd(a, p.x * p.y); atomicAdd(a + 1, p.x);
    }
    __syncthreads();

    // ---- reconstruction + epilogue ----
    int node = (b << BSH) + t;
    if (node >= N) return;
    float Ppre[NIV + 1], Qpre[NIV + 1];
    float pp = 0.0f, qq = 0.0f;
    #pragma unroll
    for (int m = 0; m < NIV; ++m) {
        Ppre[m] = pp; Qpre[m] = qq;
        pp += acc[t * STR + 2 * m];
        qq += acc[t * STR + 2 * m + 1];
    }
    Ppre[NIV] = pp; Qpre[NIV] = qq;

    float2 dsi = gds[node];
    float di = dsi.x, si = dsi.y;
    float aggv[HD];
    #pragma unroll
    for (int f = 0; f < HD; ++f) {
        int sp = splits[f], sg = signs[f];
        float w = W1[f], bbv = b1[f];
        float A, B;
        if (sg > 0)      { A = pp - Ppre[sp]; B = qq - Qpre[sp]; }
        else if (sg < 0) { A = Ppre[sp];      B = Qpre[sp]; }
        else             { A = 0.0f;          B = (bbv > 0.0f) ? qq : 0.0f; }
        float selfh = fmaxf(fmaf(w, si, bbv), 0.0f);
        aggv[f] = di * (fmaf(w, A, bbv * B) + di * selfh);
    }
    float o0 = bfc[0], o1 = bfc[1], o2 = bfc[2], o3 = bfc[3];
    #pragma unroll
    for (int f2 = 0; f2 < HD; ++f2) {
        float h = b2[f2];
        #pragma unroll
        for (int k = 0; k < HD; ++k) h = fmaf(aggv[k], W2[k * HD + f2], h);
        h = fmaxf(h, 0.0f);
        o0 = fmaf(h, Wfc[f2 * NC + 0], o0);
        o1 = fmaf(h, Wfc[f2 * NC + 1], o1);
        o2 = fmaf(h, Wfc[f2 * NC + 2], o2);
        o3 = fmaf(h, Wfc[f2 * NC + 3], o3);
    }
    ((float4*)out)[node] = make_float4(o0, o1, o2, o3);
}

extern "C" void kernel_launch(void* const* d_in, const int* in_sizes, int n_in,
                              void* d_out, int out_size, void* d_ws, size_t ws_size,
                              hipStream_t stream) {
    const float* x   = (const float*)d_in[0];
    const int*   ei  = (const int*)d_in[1];
    const float* W1  = (const float*)d_in[2];
    const float* b1  = (const float*)d_in[3];
    const float* W2  = (const float*)d_in[4];
    const float* b2  = (const float*)d_in[5];
    const float* Wfc = (const float*)d_in[6];
    const float* bfc = (const float*)d_in[7];
    float* out = (float*)d_out;

    const int N = in_sizes[0];            // 250000 (< 2^18)
    const int E = in_sizes[1] / 2;        // 4000000
    const unsigned* row = (const unsigned*)ei;
    const unsigned* col = (const unsigned*)(ei + E);

    // workspace layout
    char* ws = (char*)d_ws;
    size_t off = 0;
    unsigned* bins1 = (unsigned*)(ws + off); off += (size_t)NSB * CAP1 * 4;   // 17.8 MB
    unsigned* bins2 = (unsigned*)(ws + off); off += (size_t)NFB * CAP2 * 4;   // 21 MB
    size_t zoff = off;   // zero region: cursor1, cursor2
    int*    cursor1= (int*)(ws + off);   off += (size_t)NSB * 16 * 4;
    int*    cursor2= (int*)(ws + off);   off += (size_t)NFB * 16 * 4;
    size_t zlen = off - zoff;
    float*  dinv  = (float*)(ws + off);  off += (size_t)N * 4;
    float*  dx    = (float*)(ws + off);  off += (size_t)N * 4;
    float2* gds   = (float2*)(ws + off); off += (size_t)N * 8;
    float*  ts    = (float*)(ws + off);  off += 64;
    int*    splits= (int*)(ws + off);    off += 64;
    int*    signs = (int*)(ws + off);    off += 64;

    hipMemsetAsync(ws + zoff, 0, zlen, stream);

    const int B = 256;
    k_thr<<<1, 64, 0, stream>>>(W1, b1, ts, splits, signs);
    const int G1 = (E + CHK - 1) / CHK;   // 977
    k_part1<<<G1, B, 0, stream>>>(row, col, cursor1, bins1, E);
    k_part2<<<NSB * S2, B, 0, stream>>>(bins1, cursor1, cursor2, bins2);
    k_degdx<<<NFB, B, 0, stream>>>(bins2, cursor2, x, dinv, dx, N);
    k_s1<<<NFB, B, 0, stream>>>(bins2, cursor2, dinv, dx, gds, N);
    k_agg<<<NFB, B, 0, stream>>>(bins2, cursor2, gds, ts, splits, signs,
                                 W1, b1, W2, b2, Wfc, bfc, out, N);
}